// Round 1
// baseline (242.670 us; speedup 1.0000x reference)
//
#include <hip/hip_runtime.h>

// Lookahead depthwise conv over time:
//   y[t, b, f] = sum_{k=0..CONTEXT} x[t+k, b, f] * weight[f, k]
// with x zero-padded at the tail (tail_padding == 1 in this benchmark).
// x: (T, B, F) f32, weight: (F, CONTEXT+1) f32, y: (T, B, F) f32.
//
// Memory-bound streaming op. One thread per (b,f) column; sliding register
// window along t; TCHUNK outputs per thread (halo read amp = 20/TCHUNK).

constexpr int T = 2048;
constexpr int B = 16;
constexpr int F = 1024;
constexpr int K = 21;           // CONTEXT + 1
constexpr int BF = B * F;       // 16384 columns
constexpr int TCHUNK = 128;     // outputs per thread along t
constexpr int UNROLL = 8;       // outputs per window-shift step
constexpr int BLOCK = 256;

static_assert(TCHUNK % UNROLL == 0, "");
static_assert(T % TCHUNK == 0, "");
static_assert(BF % BLOCK == 0, "");
static_assert(TCHUNK >= K - 1, "preload guard elision requires TCHUNK >= K-1");

__global__ __launch_bounds__(BLOCK)
void lookahead_kernel(const float* __restrict__ x,
                      const float* __restrict__ weight,
                      float* __restrict__ y)
{
    const int col = blockIdx.x * BLOCK + threadIdx.x;   // 0..BF-1
    const int f   = col & (F - 1);
    const int t0  = blockIdx.y * TCHUNK;

    // Per-thread weights for this feature: 21 consecutive floats.
    float w[K];
    const float* wp = weight + f * K;
    #pragma unroll
    for (int k = 0; k < K; ++k) w[k] = wp[k];

    const float* xc = x + col;
    float*       yc = y + col;

    // Sliding window win[j] = x[t_cur + j], kept in registers.
    float win[K - 1 + UNROLL];

    // Preload first K-1 inputs. Max index t0 + K - 2 <= T - TCHUNK + K - 2 < T
    // (since TCHUNK >= K-1), so no tail guard needed here.
    #pragma unroll
    for (int k = 0; k < K - 1; ++k)
        win[k] = xc[(t0 + k) * BF];

    for (int tb = 0; tb < TCHUNK; tb += UNROLL) {
        const int t = t0 + tb;

        // Load UNROLL new inputs (tail guard is block-uniform -> scalar branch).
        #pragma unroll
        for (int u = 0; u < UNROLL; ++u) {
            const int tt = t + (K - 1) + u;
            win[K - 1 + u] = (tt < T) ? xc[tt * BF] : 0.0f;
        }

        // Compute UNROLL outputs, 21 FMAs each.
        #pragma unroll
        for (int u = 0; u < UNROLL; ++u) {
            float acc = 0.0f;
            #pragma unroll
            for (int k = 0; k < K; ++k)
                acc = fmaf(win[u + k], w[k], acc);
            yc[(t + u) * BF] = acc;
        }

        // Shift window by UNROLL (static indices -> register moves, no scratch).
        #pragma unroll
        for (int k = 0; k < K - 1; ++k)
            win[k] = win[k + UNROLL];
    }
}

extern "C" void kernel_launch(void* const* d_in, const int* in_sizes, int n_in,
                              void* d_out, int out_size, void* d_ws, size_t ws_size,
                              hipStream_t stream) {
    const float* x      = (const float*)d_in[0];
    const float* weight = (const float*)d_in[1];
    // d_in[2] is tail_padding; always 1 in this benchmark (out_size == T*B*F).
    float* y = (float*)d_out;

    dim3 grid(BF / BLOCK, T / TCHUNK);
    lookahead_kernel<<<grid, dim3(BLOCK), 0, stream>>>(x, weight, y);
}

// Round 2
// 238.653 us; speedup vs baseline: 1.0168x; 1.0168x over previous
//
#include <hip/hip_runtime.h>

// Lookahead depthwise conv over time:
//   y[t, b, f] = sum_{k=0..CONTEXT} x[t+k, b, f] * weight[f, k]
// x: (T, B, F) f32, weight: (F, CONTEXT+1) f32, y: (T, B, F) f32.
//
// Memory-bound streaming op. One thread per (b,f) column; sliding register
// window along t. R2: TCHUNK=64 (grid 2048 blocks -> 8192 waves = 100% of
// wave slots; R1's 128 capped occupancy at 50%) + prefetch double-buffer so
// 8 loads are in flight while computing (R1 exposed full HBM latency).

constexpr int T = 2048;
constexpr int B = 16;
constexpr int F = 1024;
constexpr int K = 21;           // CONTEXT + 1
constexpr int BF = B * F;       // 16384 columns
constexpr int TCHUNK = 64;      // outputs per thread along t
constexpr int UNROLL = 8;       // outputs per window-shift step
constexpr int BLOCK = 256;

static_assert(TCHUNK % UNROLL == 0, "");
static_assert(T % TCHUNK == 0, "");
static_assert(BF % BLOCK == 0, "");
static_assert(TCHUNK >= K - 1, "preload guard elision requires TCHUNK >= K-1");

__global__ __launch_bounds__(BLOCK)
void lookahead_kernel(const float* __restrict__ x,
                      const float* __restrict__ weight,
                      float* __restrict__ y)
{
    const int col = blockIdx.x * BLOCK + threadIdx.x;   // 0..BF-1
    const int f   = col & (F - 1);
    const int t0  = blockIdx.y * TCHUNK;

    // Per-thread weights for this feature: 21 consecutive floats.
    float w[K];
    const float* wp = weight + f * K;
    #pragma unroll
    for (int k = 0; k < K; ++k) w[k] = wp[k];

    const float* xc = x + col;
    float*       yc = y + col;

    // Sliding window win[j] = x[t_cur + j] in registers, plus a prefetch
    // buffer nxt[] holding the next UNROLL inputs (in flight during compute).
    float win[K - 1 + UNROLL];
    float nxt[UNROLL];

    // Preload first K-1 window inputs. Max index t0 + K - 2 < T since
    // TCHUNK >= K-1, so no guard needed.
    #pragma unroll
    for (int k = 0; k < K - 1; ++k)
        win[k] = xc[(t0 + k) * BF];

    // First prefetch batch: t0 + K-1 + u.
    #pragma unroll
    for (int u = 0; u < UNROLL; ++u) {
        const int tt = t0 + (K - 1) + u;
        nxt[u] = (tt < T) ? xc[tt * BF] : 0.0f;
    }

    for (int tb = 0; tb < TCHUNK; tb += UNROLL) {
        const int t = t0 + tb;

        // Commit prefetched values into the window.
        #pragma unroll
        for (int u = 0; u < UNROLL; ++u)
            win[K - 1 + u] = nxt[u];

        // Issue next iteration's loads (uniform guard -> scalar branch).
        #pragma unroll
        for (int u = 0; u < UNROLL; ++u) {
            const int tt = t + UNROLL + (K - 1) + u;
            nxt[u] = (tt < T) ? xc[tt * BF] : 0.0f;
        }

        // Compute UNROLL outputs, 21 FMAs each (overlaps the loads above).
        #pragma unroll
        for (int u = 0; u < UNROLL; ++u) {
            float acc = 0.0f;
            #pragma unroll
            for (int k = 0; k < K; ++k)
                acc = fmaf(win[u + k], w[k], acc);
            yc[(t + u) * BF] = acc;
        }

        // Shift window by UNROLL (static indices -> register moves).
        #pragma unroll
        for (int k = 0; k < K - 1; ++k)
            win[k] = win[k + UNROLL];
    }
}

extern "C" void kernel_launch(void* const* d_in, const int* in_sizes, int n_in,
                              void* d_out, int out_size, void* d_ws, size_t ws_size,
                              hipStream_t stream) {
    const float* x      = (const float*)d_in[0];
    const float* weight = (const float*)d_in[1];
    // d_in[2] is tail_padding; always 1 in this benchmark (out_size == T*B*F).
    float* y = (float*)d_out;

    dim3 grid(BF / BLOCK, T / TCHUNK);
    lookahead_kernel<<<grid, dim3(BLOCK), 0, stream>>>(x, weight, y);
}